// Round 1
// baseline (1107.143 us; speedup 1.0000x reference)
//
#include <hip/hip_runtime.h>
#include <hip/hip_bf16.h>
#include <math.h>

// ---------------------------------------------------------------------------
// GIN 2-layer forward:
//   agg1 = segment_sum(x[src], dst); h = relu(relu((x+agg1)@W1a+b1a)@W2a+b2a)
//   agg2 = segment_sum(h[src], dst); z = relu((h+agg2)@W1b+b1b)@W2b+b2b
//   out = log_softmax(z, axis=1)
// N=100000, E=1200000, IN=64, HID=128, OUT=40, all float32.
// ---------------------------------------------------------------------------

#define WS_ALIGN 256

// --- dtype sniff: edge_index may arrive as int64 (ref says jnp.int64) or as
// int32 (JAX x64-disabled canonicalization). If int64, the odd 32-bit words
// (high halves, values < 2^17) are all zero. Sample 4096 entries.
__global__ __launch_bounds__(256) void sniff_kernel(const unsigned int* __restrict__ ew,
                                                    unsigned int* __restrict__ flag, int E) {
  unsigned int acc = 0;
  int i = threadIdx.x;
  for (int j = 0; j < 16; ++j) {
    long long s = ((long long)(i * 16 + j) * 292 + 7) % E;   // within src array
    acc |= ew[2 * (size_t)s + 1];                            // safe under both dtypes
  }
  if (acc) atomicOr(flag, 1u);   // nonzero -> int32 layout
}

// --- scatter-add aggregation: one wave per edge (grid-stride), lane f adds
// X[src][f] into AGG[dst][f]. F in {64,128}.
template<int F>
__global__ __launch_bounds__(256) void scatter_add_kernel(
    const unsigned int* __restrict__ ew, const unsigned int* __restrict__ flag,
    const float* __restrict__ X, float* __restrict__ AGG, int E) {
  const bool is64 = (*flag == 0u);
  const int lane = threadIdx.x & 63;
  const int wid  = blockIdx.x * (blockDim.x >> 6) + (threadIdx.x >> 6);
  const int nw   = gridDim.x * (blockDim.x >> 6);
  for (int e = wid; e < E; e += nw) {
    int s, d;
    if (is64) { s = (int)ew[2 * (size_t)e];       d = (int)ew[2 * (size_t)(E + e)]; }
    else      { s = (int)ew[(size_t)e];           d = (int)ew[(size_t)E + e]; }
    const float* xs = X + (size_t)s * F;
    float*       ad = AGG + (size_t)d * F;
#pragma unroll
    for (int f = lane; f < F; f += 64)
      atomicAdd(&ad[f], xs[f]);
  }
}

// --- fused tile GEMM: out[n][fo] = act((A1[n]+A2[n]) @ W + b), row-major.
// Block: 256 threads, 64-node x 64-fo tile, 4x4 register tile per thread.
// A staged in LDS with a +4*row column rotation (2-way banks max, free),
// W chunk staged in LDS (zero-padded past Fo).
template<int Fi, bool ADD, bool RELU>
__global__ __launch_bounds__(256) void gemm_tile(
    const float* __restrict__ A1, const float* __restrict__ A2,
    const float* __restrict__ W, const float* __restrict__ bias,
    float* __restrict__ out, int N, int Fo) {
  __shared__ float As[64 * Fi];
  __shared__ float Ws[Fi * 64];
  const int t   = threadIdx.x;
  const int n0  = blockIdx.x * 64;
  const int fo0 = blockIdx.y * 64;

  // stage A tile (rotated columns): value A[n0+row][k] lives at
  // As[row*Fi + ((k + 4*row) % Fi)]
  const int rowF4 = Fi / 4;
  for (int i = t; i < 64 * rowF4; i += 256) {
    int row = i / rowF4;
    int c4  = (i % rowF4) * 4;
    int n   = n0 + row;
    float4 v = make_float4(0.f, 0.f, 0.f, 0.f);
    if (n < N) {
      v = *reinterpret_cast<const float4*>(A1 + (size_t)n * Fi + c4);
      if (ADD) {
        float4 u = *reinterpret_cast<const float4*>(A2 + (size_t)n * Fi + c4);
        v.x += u.x; v.y += u.y; v.z += u.z; v.w += u.w;
      }
    }
    int sc = (c4 + row * 4) % Fi;   // multiple of 4, no intra-float4 wrap
    *reinterpret_cast<float4*>(&As[row * Fi + sc]) = v;
  }
  // stage W chunk [Fi][64] for fo0..fo0+63 (zero-pad past Fo)
  for (int i = t; i < Fi * 64; i += 256) {
    int k = i >> 6, c = i & 63;
    int fo = fo0 + c;
    Ws[i] = (fo < Fo) ? W[(size_t)k * Fo + fo] : 0.f;
  }
  __syncthreads();

  const int c = t & 15, r = t >> 4;   // 16 fo-cols x 16 node-rows
  float acc[4][4];
#pragma unroll
  for (int i = 0; i < 4; ++i)
#pragma unroll
    for (int j = 0; j < 4; ++j) acc[i][j] = 0.f;

#pragma unroll 4
  for (int k = 0; k < Fi; ++k) {
    float4 w = *reinterpret_cast<const float4*>(&Ws[k * 64 + c * 4]);
    float a[4];
#pragma unroll
    for (int i = 0; i < 4; ++i) {
      int row = r * 4 + i;
      a[i] = As[row * Fi + ((k + row * 4) % Fi)];
    }
#pragma unroll
    for (int i = 0; i < 4; ++i) {
      acc[i][0] += a[i] * w.x; acc[i][1] += a[i] * w.y;
      acc[i][2] += a[i] * w.z; acc[i][3] += a[i] * w.w;
    }
  }

#pragma unroll
  for (int i = 0; i < 4; ++i) {
    int n = n0 + r * 4 + i;
    if (n >= N) continue;
#pragma unroll
    for (int j = 0; j < 4; ++j) {
      int fo = fo0 + c * 4 + j;
      if (fo >= Fo) continue;
      float v = acc[i][j] + bias[fo];
      if (RELU) v = fmaxf(v, 0.f);
      out[(size_t)n * Fo + fo] = v;
    }
  }
}

// --- final 40x40 GEMM + row log-softmax, one wave per node (grid-stride).
__global__ __launch_bounds__(256) void gemm_lsm_kernel(
    const float* __restrict__ A, const float* __restrict__ W,
    const float* __restrict__ bias, float* __restrict__ out, int N) {
  __shared__ float Wl[40 * 40];
  __shared__ float bl[40];
  int t = threadIdx.x;
  for (int i = t; i < 1600; i += 256) Wl[i] = W[i];
  if (t < 40) bl[t] = bias[t];
  __syncthreads();

  const int lane = t & 63;
  const int wid  = blockIdx.x * 4 + (t >> 6);
  const int nw   = gridDim.x * 4;
  for (int n = wid; n < N; n += nw) {
    const float* a = A + (size_t)n * 40;
    float acc = (lane < 40) ? bl[lane] : 0.f;
    if (lane < 40) {
#pragma unroll 8
      for (int k = 0; k < 40; ++k)
        acc += a[k] * Wl[k * 40 + lane];
    }
    float m = (lane < 40) ? acc : -3.4e38f;
#pragma unroll
    for (int o = 32; o >= 1; o >>= 1) m = fmaxf(m, __shfl_xor(m, o, 64));
    float ex = (lane < 40) ? expf(acc - m) : 0.f;
    float ssum = ex;
#pragma unroll
    for (int o = 32; o >= 1; o >>= 1) ssum += __shfl_xor(ssum, o, 64);
    if (lane < 40) out[(size_t)n * 40 + lane] = acc - m - logf(ssum);
  }
}

extern "C" void kernel_launch(void* const* d_in, const int* in_sizes, int n_in,
                              void* d_out, int out_size, void* d_ws, size_t ws_size,
                              hipStream_t stream) {
  const float*        x   = (const float*)d_in[0];
  const unsigned int* ew  = (const unsigned int*)d_in[1];
  const float*        W1a = (const float*)d_in[2];
  const float*        b1a = (const float*)d_in[3];
  const float*        W2a = (const float*)d_in[4];
  const float*        b2a = (const float*)d_in[5];
  const float*        W1b = (const float*)d_in[6];
  const float*        b1b = (const float*)d_in[7];
  const float*        W2b = (const float*)d_in[8];
  const float*        b2b = (const float*)d_in[9];

  const int N = in_sizes[0] / 64;     // 100000
  const int E = in_sizes[1] / 2;      // 1200000
  float* out = (float*)d_out;

  char* ws = (char*)d_ws;
  unsigned int* flag = (unsigned int*)ws;
  float* bufAgg = (float*)(ws + WS_ALIGN);            // [N,128] (agg1 uses [N,64])
  float* bufA   = bufAgg + (size_t)N * 128;           // [N,128] mid / [N,40] mid2
  float* bufH   = bufA   + (size_t)N * 128;           // [N,128] h

  hipMemsetAsync(flag, 0, 4, stream);
  sniff_kernel<<<1, 256, 0, stream>>>(ew, flag, E);

  // conv1 aggregation
  hipMemsetAsync(bufAgg, 0, (size_t)N * 64 * sizeof(float), stream);
  scatter_add_kernel<64><<<4096, 256, 0, stream>>>(ew, flag, x, bufAgg, E);

  dim3 gNodes((N + 63) / 64, 2);
  // mid = relu((x+agg1)@W1a + b1a)
  gemm_tile<64, true, true><<<gNodes, 256, 0, stream>>>(x, bufAgg, W1a, b1a, bufA, N, 128);
  // h = relu(mid@W2a + b2a)
  gemm_tile<128, false, true><<<gNodes, 256, 0, stream>>>(bufA, nullptr, W2a, b2a, bufH, N, 128);

  // conv2 aggregation
  hipMemsetAsync(bufAgg, 0, (size_t)N * 128 * sizeof(float), stream);
  scatter_add_kernel<128><<<4096, 256, 0, stream>>>(ew, flag, bufH, bufAgg, E);

  dim3 gNodes3((N + 63) / 64, 1);
  // mid2 = relu((h+agg2)@W1b + b1b)   [N,40]
  gemm_tile<128, true, true><<<gNodes3, 256, 0, stream>>>(bufH, bufAgg, W1b, b1b, bufA, N, 40);

  // out = log_softmax(mid2@W2b + b2b)
  gemm_lsm_kernel<<<1024, 256, 0, stream>>>(bufA, W2b, b2b, out, N);
}

// Round 2
// 646.847 us; speedup vs baseline: 1.7116x; 1.7116x over previous
//
#include <hip/hip_runtime.h>
#include <hip/hip_bf16.h>
#include <math.h>

// ---------------------------------------------------------------------------
// GIN 2-layer forward, CSR-gather aggregation (no f32 atomics):
//   agg1 = segment_sum(x[src], dst); h = relu(relu((x+agg1)@W1a+b1a)@W2a+b2a)
//   agg2 = segment_sum(h[src], dst); z = relu((h+agg2)@W1b+b1b)@W2b+b2b
//   out = log_softmax(z, axis=1)
// N=100000, E=1200000, IN=64, HID=128, OUT=40, float32.
// ---------------------------------------------------------------------------

#define WS_ALIGN 256
#define SCAN_T 256
#define SCAN_E 1024   // elements per scan block

// --- dtype sniff: edge_index may be int64 (ref) or int32 (x64-disabled JAX).
__global__ __launch_bounds__(256) void sniff_kernel(const unsigned int* __restrict__ ew,
                                                    unsigned int* __restrict__ flag, int E) {
  unsigned int acc = 0;
  int i = threadIdx.x;
  for (int j = 0; j < 16; ++j) {
    long long s = ((long long)(i * 16 + j) * 292 + 7) % E;
    acc |= ew[2 * (size_t)s + 1];
  }
  if (acc) atomicOr(flag, 1u);   // nonzero -> int32 layout
}

// --- degree histogram over dst
__global__ __launch_bounds__(256) void hist_kernel(
    const unsigned int* __restrict__ ew, const unsigned int* __restrict__ flag,
    int* __restrict__ deg, int E) {
  const bool is64 = (*flag == 0u);
  int i = blockIdx.x * blockDim.x + threadIdx.x;
  int stride = gridDim.x * blockDim.x;
  for (int e = i; e < E; e += stride) {
    int d = is64 ? (int)ew[2 * (size_t)(E + e)] : (int)ew[(size_t)E + e];
    atomicAdd(&deg[d], 1);
  }
}

// --- 3-pass exclusive scan of deg[N] -> rowptr[N+1] (in place) + wptr copy
__global__ __launch_bounds__(SCAN_T) void scan1_kernel(const int* __restrict__ deg,
                                                       int* __restrict__ bsum, int N) {
  __shared__ int s[SCAN_T];
  int b = blockIdx.x, t = threadIdx.x;
  int base = b * SCAN_E + t * 4;
  int v = 0;
#pragma unroll
  for (int k = 0; k < 4; ++k) { int i = base + k; if (i < N) v += deg[i]; }
  s[t] = v; __syncthreads();
  for (int off = SCAN_T / 2; off >= 1; off >>= 1) {
    if (t < off) s[t] += s[t + off];
    __syncthreads();
  }
  if (t == 0) bsum[b] = s[0];
}

__global__ void scan2_kernel(int* __restrict__ bsum, int nb) {
  if (blockIdx.x == 0 && threadIdx.x == 0) {
    int run = 0;
    for (int i = 0; i < nb; ++i) { int v = bsum[i]; bsum[i] = run; run += v; }
    bsum[nb] = run;
  }
}

__global__ __launch_bounds__(SCAN_T) void scan3_kernel(
    int* __restrict__ rowptr /* in: deg, out: exclusive scan */,
    int* __restrict__ wptr, const int* __restrict__ bsum, int N, int E) {
  __shared__ int s[SCAN_T];
  int b = blockIdx.x, t = threadIdx.x;
  int base = b * SCAN_E + t * 4;
  int d[4]; int v = 0;
#pragma unroll
  for (int k = 0; k < 4; ++k) { int i = base + k; d[k] = (i < N) ? rowptr[i] : 0; v += d[k]; }
  s[t] = v; __syncthreads();
  for (int off = 1; off < SCAN_T; off <<= 1) {
    int u = (t >= off) ? s[t - off] : 0;
    __syncthreads();
    s[t] += u;
    __syncthreads();
  }
  int exc = s[t] - v + bsum[b];
#pragma unroll
  for (int k = 0; k < 4; ++k) {
    int i = base + k;
    if (i < N) { rowptr[i] = exc; wptr[i] = exc; exc += d[k]; }
  }
  if (b == 0 && t == 0) rowptr[N] = E;
}

// --- bucket fill: col[pos] = src, pos = wptr[dst]++
__global__ __launch_bounds__(256) void fill_kernel(
    const unsigned int* __restrict__ ew, const unsigned int* __restrict__ flag,
    int* __restrict__ wptr, int* __restrict__ col, int E) {
  const bool is64 = (*flag == 0u);
  int i = blockIdx.x * blockDim.x + threadIdx.x;
  int stride = gridDim.x * blockDim.x;
  for (int e = i; e < E; e += stride) {
    int s, d;
    if (is64) { s = (int)ew[2 * (size_t)e]; d = (int)ew[2 * (size_t)(E + e)]; }
    else      { s = (int)ew[(size_t)e];     d = (int)ew[(size_t)E + e]; }
    int pos = atomicAdd(&wptr[d], 1);
    col[pos] = s;
  }
}

// --- gather: out[n] = X[n] + sum_{j in row n} X[col[j]]  (self-term fused)
// One wave per node. F=64: 1 float/lane; F=128: float2/lane.
template<int F>
__global__ __launch_bounds__(256) void gather_kernel(
    const float* __restrict__ X, const int* __restrict__ rowptr,
    const int* __restrict__ col, float* __restrict__ out, int N) {
  const int lane = threadIdx.x & 63;
  const int n = blockIdx.x * 4 + (threadIdx.x >> 6);
  if (n >= N) return;
  const int beg = rowptr[n], end = rowptr[n + 1];
  if constexpr (F == 64) {
    float a0 = X[(size_t)n * 64 + lane], a1 = 0.f, a2 = 0.f, a3 = 0.f;
    int j = beg;
    for (; j + 4 <= end; j += 4) {
      int c0 = col[j], c1 = col[j + 1], c2 = col[j + 2], c3 = col[j + 3];
      a0 += X[(size_t)c0 * 64 + lane];
      a1 += X[(size_t)c1 * 64 + lane];
      a2 += X[(size_t)c2 * 64 + lane];
      a3 += X[(size_t)c3 * 64 + lane];
    }
    for (; j < end; ++j) a0 += X[(size_t)col[j] * 64 + lane];
    out[(size_t)n * 64 + lane] = a0 + a1 + a2 + a3;
  } else {
    const float2* X2 = (const float2*)X;
    float2 a0 = X2[(size_t)n * 64 + lane];
    float2 a1 = make_float2(0.f, 0.f), a2 = make_float2(0.f, 0.f), a3 = make_float2(0.f, 0.f);
    int j = beg;
    for (; j + 4 <= end; j += 4) {
      int c0 = col[j], c1 = col[j + 1], c2 = col[j + 2], c3 = col[j + 3];
      float2 v0 = X2[(size_t)c0 * 64 + lane]; a0.x += v0.x; a0.y += v0.y;
      float2 v1 = X2[(size_t)c1 * 64 + lane]; a1.x += v1.x; a1.y += v1.y;
      float2 v2 = X2[(size_t)c2 * 64 + lane]; a2.x += v2.x; a2.y += v2.y;
      float2 v3 = X2[(size_t)c3 * 64 + lane]; a3.x += v3.x; a3.y += v3.y;
    }
    for (; j < end; ++j) {
      float2 v = X2[(size_t)col[j] * 64 + lane]; a0.x += v.x; a0.y += v.y;
    }
    float2 r = make_float2(a0.x + a1.x + a2.x + a3.x, a0.y + a1.y + a2.y + a3.y);
    ((float2*)out)[(size_t)n * 64 + lane] = r;
  }
}

// --- tile GEMM: out[n][fo] = act(A[n] @ W + b). 64x64 tile, 4x4 per thread.
template<int Fi, bool RELU>
__global__ __launch_bounds__(256) void gemm_tile(
    const float* __restrict__ A1,
    const float* __restrict__ W, const float* __restrict__ bias,
    float* __restrict__ out, int N, int Fo) {
  __shared__ float As[64 * Fi];
  __shared__ float Ws[Fi * 64];
  const int t   = threadIdx.x;
  const int n0  = blockIdx.x * 64;
  const int fo0 = blockIdx.y * 64;

  const int rowF4 = Fi / 4;
  for (int i = t; i < 64 * rowF4; i += 256) {
    int row = i / rowF4;
    int c4  = (i % rowF4) * 4;
    int n   = n0 + row;
    float4 v = make_float4(0.f, 0.f, 0.f, 0.f);
    if (n < N) v = *reinterpret_cast<const float4*>(A1 + (size_t)n * Fi + c4);
    int sc = (c4 + row * 4) % Fi;
    *reinterpret_cast<float4*>(&As[row * Fi + sc]) = v;
  }
  for (int i = t; i < Fi * 64; i += 256) {
    int k = i >> 6, c = i & 63;
    int fo = fo0 + c;
    Ws[i] = (fo < Fo) ? W[(size_t)k * Fo + fo] : 0.f;
  }
  __syncthreads();

  const int c = t & 15, r = t >> 4;
  float acc[4][4];
#pragma unroll
  for (int i = 0; i < 4; ++i)
#pragma unroll
    for (int j = 0; j < 4; ++j) acc[i][j] = 0.f;

#pragma unroll 4
  for (int k = 0; k < Fi; ++k) {
    float4 w = *reinterpret_cast<const float4*>(&Ws[k * 64 + c * 4]);
    float a[4];
#pragma unroll
    for (int i = 0; i < 4; ++i) {
      int row = r * 4 + i;
      a[i] = As[row * Fi + ((k + row * 4) % Fi)];
    }
#pragma unroll
    for (int i = 0; i < 4; ++i) {
      acc[i][0] += a[i] * w.x; acc[i][1] += a[i] * w.y;
      acc[i][2] += a[i] * w.z; acc[i][3] += a[i] * w.w;
    }
  }

#pragma unroll
  for (int i = 0; i < 4; ++i) {
    int n = n0 + r * 4 + i;
    if (n >= N) continue;
#pragma unroll
    for (int j = 0; j < 4; ++j) {
      int fo = fo0 + c * 4 + j;
      if (fo >= Fo) continue;
      float v = acc[i][j] + bias[fo];
      if (RELU) v = fmaxf(v, 0.f);
      out[(size_t)n * Fo + fo] = v;
    }
  }
}

// --- final 40x40 GEMM + row log-softmax, one wave per node.
__global__ __launch_bounds__(256) void gemm_lsm_kernel(
    const float* __restrict__ A, const float* __restrict__ W,
    const float* __restrict__ bias, float* __restrict__ out, int N) {
  __shared__ float Wl[40 * 40];
  __shared__ float bl[40];
  int t = threadIdx.x;
  for (int i = t; i < 1600; i += 256) Wl[i] = W[i];
  if (t < 40) bl[t] = bias[t];
  __syncthreads();

  const int lane = t & 63;
  const int wid  = blockIdx.x * 4 + (t >> 6);
  const int nw   = gridDim.x * 4;
  for (int n = wid; n < N; n += nw) {
    const float* a = A + (size_t)n * 40;
    float acc = (lane < 40) ? bl[lane] : 0.f;
    if (lane < 40) {
#pragma unroll 8
      for (int k = 0; k < 40; ++k)
        acc += a[k] * Wl[k * 40 + lane];
    }
    float m = (lane < 40) ? acc : -3.4e38f;
#pragma unroll
    for (int o = 32; o >= 1; o >>= 1) m = fmaxf(m, __shfl_xor(m, o, 64));
    float ex = (lane < 40) ? expf(acc - m) : 0.f;
    float ssum = ex;
#pragma unroll
    for (int o = 32; o >= 1; o >>= 1) ssum += __shfl_xor(ssum, o, 64);
    if (lane < 40) out[(size_t)n * 40 + lane] = acc - m - logf(ssum);
  }
}

extern "C" void kernel_launch(void* const* d_in, const int* in_sizes, int n_in,
                              void* d_out, int out_size, void* d_ws, size_t ws_size,
                              hipStream_t stream) {
  const float*        x   = (const float*)d_in[0];
  const unsigned int* ew  = (const unsigned int*)d_in[1];
  const float*        W1a = (const float*)d_in[2];
  const float*        b1a = (const float*)d_in[3];
  const float*        W2a = (const float*)d_in[4];
  const float*        b2a = (const float*)d_in[5];
  const float*        W1b = (const float*)d_in[6];
  const float*        b1b = (const float*)d_in[7];
  const float*        W2b = (const float*)d_in[8];
  const float*        b2b = (const float*)d_in[9];

  const int N = in_sizes[0] / 64;     // 100000
  const int E = in_sizes[1] / 2;      // 1200000
  float* out = (float*)d_out;

  char* ws = (char*)d_ws;
  unsigned int* flag = (unsigned int*)ws;
  int* rowptr = (int*)(ws + WS_ALIGN);                 // N+1 (starts life as deg)
  int* wptr   = rowptr + (N + 2);                      // N
  int* bsum   = wptr + N;                              // nb+1 (<= 128)
  int* col    = bsum + 160;                            // E
  char* fbase = (char*)(col + E);
  fbase += (WS_ALIGN - ((size_t)fbase % WS_ALIGN)) % WS_ALIGN;
  float* bufXA = (float*)fbase;                        // [N,128] (x+agg1 uses [N,64]; h+agg2 uses [N,128])
  float* bufA  = bufXA + (size_t)N * 128;              // [N,128] mid / [N,40] mid2
  float* bufH  = bufA  + (size_t)N * 128;              // [N,128] h

  const int nb = (N + SCAN_E - 1) / SCAN_E;

  hipMemsetAsync(flag, 0, 4, stream);
  sniff_kernel<<<1, 256, 0, stream>>>(ew, flag, E);

  // --- CSR build (per launch; deterministic work, order-free sums)
  hipMemsetAsync(rowptr, 0, (size_t)(N + 1) * sizeof(int), stream);
  hist_kernel<<<2048, 256, 0, stream>>>(ew, flag, rowptr, E);
  scan1_kernel<<<nb, SCAN_T, 0, stream>>>(rowptr, bsum, N);
  scan2_kernel<<<1, 64, 0, stream>>>(bsum, nb);
  scan3_kernel<<<nb, SCAN_T, 0, stream>>>(rowptr, wptr, bsum, N, E);
  fill_kernel<<<2048, 256, 0, stream>>>(ew, flag, wptr, col, E);

  const int gGather = (N + 3) / 4;

  // --- conv1: xa = x + agg1; mid = relu(xa@W1a+b1a); h = relu(mid@W2a+b2a)
  gather_kernel<64><<<gGather, 256, 0, stream>>>(x, rowptr, col, bufXA, N);
  dim3 gNodes((N + 63) / 64, 2);
  gemm_tile<64, true><<<gNodes, 256, 0, stream>>>(bufXA, W1a, b1a, bufA, N, 128);
  gemm_tile<128, true><<<gNodes, 256, 0, stream>>>(bufA, W2a, b2a, bufH, N, 128);

  // --- conv2: ha = h + agg2; mid2 = relu(ha@W1b+b1b); out = lsm(mid2@W2b+b2b)
  gather_kernel<128><<<gGather, 256, 0, stream>>>(bufH, rowptr, col, bufXA, N);
  dim3 gNodes3((N + 63) / 64, 1);
  gemm_tile<128, true><<<gNodes3, 256, 0, stream>>>(bufXA, W1b, b1b, bufA, N, 40);
  gemm_lsm_kernel<<<1024, 256, 0, stream>>>(bufA, W2b, b2b, out, N);
}

// Round 3
// 383.020 us; speedup vs baseline: 2.8906x; 1.6888x over previous
//
#include <hip/hip_runtime.h>
#include <hip/hip_bf16.h>
#include <math.h>

// ---------------------------------------------------------------------------
// GIN 2-layer forward. CSR-gather aggregation (f32 sums), bf16 MFMA GEMMs.
//   xa = x + seg_sum(x[src],dst); mid = relu(xa@W1a+b1a); h = relu(mid@W2a+b2a)
//   ha = h + seg_sum(h[src],dst); mid2 = relu(ha@W1b+b1b)
//   out = log_softmax(mid2@W2b+b2b)
// N=100000, E=1200000, IN=64, HID=128, OUT=40.
// ---------------------------------------------------------------------------

#define WS_ALIGN 256
#define SCAN_T 256
#define SCAN_E 1024

typedef __attribute__((ext_vector_type(8))) __bf16 bf16x8;
typedef __attribute__((ext_vector_type(4))) float f32x4;

__device__ inline unsigned short f2b(float f) {      // RNE f32->bf16
  unsigned int x = __float_as_uint(f);
  return (unsigned short)((x + 0x7fffu + ((x >> 16) & 1u)) >> 16);
}
__device__ inline float b2f(unsigned short u) {
  return __uint_as_float(((unsigned int)u) << 16);
}

// --- dtype sniff: edge_index may be int64 (ref) or int32 (x64-disabled JAX).
__global__ __launch_bounds__(256) void sniff_kernel(const unsigned int* __restrict__ ew,
                                                    unsigned int* __restrict__ flag, int E) {
  unsigned int acc = 0;
  int i = threadIdx.x;
  for (int j = 0; j < 16; ++j) {
    long long s = ((long long)(i * 16 + j) * 292 + 7) % E;
    acc |= ew[2 * (size_t)s + 1];
  }
  if (acc) atomicOr(flag, 1u);   // nonzero -> int32 layout
}

// --- degree histogram over dst
__global__ __launch_bounds__(256) void hist_kernel(
    const unsigned int* __restrict__ ew, const unsigned int* __restrict__ flag,
    int* __restrict__ deg, int E) {
  const bool is64 = (*flag == 0u);
  int i = blockIdx.x * blockDim.x + threadIdx.x;
  int stride = gridDim.x * blockDim.x;
  for (int e = i; e < E; e += stride) {
    int d = is64 ? (int)ew[2 * (size_t)(E + e)] : (int)ew[(size_t)E + e];
    atomicAdd(&deg[d], 1);
  }
}

// --- 3-pass exclusive scan of deg[N] -> rowptr[N+1] (in place) + wptr copy
__global__ __launch_bounds__(SCAN_T) void scan1_kernel(const int* __restrict__ deg,
                                                       int* __restrict__ bsum, int N) {
  __shared__ int s[SCAN_T];
  int b = blockIdx.x, t = threadIdx.x;
  int base = b * SCAN_E + t * 4;
  int v = 0;
#pragma unroll
  for (int k = 0; k < 4; ++k) { int i = base + k; if (i < N) v += deg[i]; }
  s[t] = v; __syncthreads();
  for (int off = SCAN_T / 2; off >= 1; off >>= 1) {
    if (t < off) s[t] += s[t + off];
    __syncthreads();
  }
  if (t == 0) bsum[b] = s[0];
}

__global__ void scan2_kernel(int* __restrict__ bsum, int nb) {
  if (blockIdx.x == 0 && threadIdx.x == 0) {
    int run = 0;
    for (int i = 0; i < nb; ++i) { int v = bsum[i]; bsum[i] = run; run += v; }
    bsum[nb] = run;
  }
}

__global__ __launch_bounds__(SCAN_T) void scan3_kernel(
    int* __restrict__ rowptr, int* __restrict__ wptr,
    const int* __restrict__ bsum, int N, int E) {
  __shared__ int s[SCAN_T];
  int b = blockIdx.x, t = threadIdx.x;
  int base = b * SCAN_E + t * 4;
  int d[4]; int v = 0;
#pragma unroll
  for (int k = 0; k < 4; ++k) { int i = base + k; d[k] = (i < N) ? rowptr[i] : 0; v += d[k]; }
  s[t] = v; __syncthreads();
  for (int off = 1; off < SCAN_T; off <<= 1) {
    int u = (t >= off) ? s[t - off] : 0;
    __syncthreads();
    s[t] += u;
    __syncthreads();
  }
  int exc = s[t] - v + bsum[b];
#pragma unroll
  for (int k = 0; k < 4; ++k) {
    int i = base + k;
    if (i < N) { rowptr[i] = exc; wptr[i] = exc; exc += d[k]; }
  }
  if (b == 0 && t == 0) rowptr[N] = E;
}

// --- bucket fill: col[pos] = src, pos = wptr[dst]++
__global__ __launch_bounds__(256) void fill_kernel(
    const unsigned int* __restrict__ ew, const unsigned int* __restrict__ flag,
    int* __restrict__ wptr, int* __restrict__ col, int E) {
  const bool is64 = (*flag == 0u);
  int i = blockIdx.x * blockDim.x + threadIdx.x;
  int stride = gridDim.x * blockDim.x;
  for (int e = i; e < E; e += stride) {
    int s, d;
    if (is64) { s = (int)ew[2 * (size_t)e]; d = (int)ew[2 * (size_t)(E + e)]; }
    else      { s = (int)ew[(size_t)e];     d = (int)ew[(size_t)E + e]; }
    int pos = atomicAdd(&wptr[d], 1);
    col[pos] = s;
  }
}

// --- weight transpose + cast: Wt[fo][k] = bf16(W[k][fo]), zero-pad fo>=Fo
__global__ __launch_bounds__(256) void transw_kernel(
    const float* __restrict__ W, unsigned short* __restrict__ Wt,
    int Fi, int Fo, int FoPad) {
  int i = blockIdx.x * 256 + threadIdx.x;
  if (i >= FoPad * Fi) return;
  int fo = i / Fi, k = i - fo * Fi;
  float v = (fo < Fo) ? W[(size_t)k * Fo + fo] : 0.f;
  Wt[i] = f2b(v);
}

// --- gather conv1: out_bf16[n] = x[n] + sum_{j} x[col[j]]   (x is f32 [N,64])
__global__ __launch_bounds__(256) void gather64_kernel(
    const float* __restrict__ X, const int* __restrict__ rowptr,
    const int* __restrict__ col, unsigned short* __restrict__ out, int N) {
  const int lane = threadIdx.x & 63;
  const int n = blockIdx.x * 4 + (threadIdx.x >> 6);
  if (n >= N) return;
  const int beg = rowptr[n], end = rowptr[n + 1];
  float a0 = X[(size_t)n * 64 + lane], a1 = 0.f, a2 = 0.f, a3 = 0.f;
  int j = beg;
  for (; j + 4 <= end; j += 4) {
    int c0 = col[j], c1 = col[j + 1], c2 = col[j + 2], c3 = col[j + 3];
    a0 += X[(size_t)c0 * 64 + lane];
    a1 += X[(size_t)c1 * 64 + lane];
    a2 += X[(size_t)c2 * 64 + lane];
    a3 += X[(size_t)c3 * 64 + lane];
  }
  for (; j < end; ++j) a0 += X[(size_t)col[j] * 64 + lane];
  out[(size_t)n * 64 + lane] = f2b(a0 + a1 + a2 + a3);
}

// --- gather conv2: bf16 [N,128] in/out, f32 sums; lane handles 2 features.
__global__ __launch_bounds__(256) void gather128_kernel(
    const unsigned int* __restrict__ X, const int* __restrict__ rowptr,
    const int* __restrict__ col, unsigned int* __restrict__ out, int N) {
  const int lane = threadIdx.x & 63;
  const int n = blockIdx.x * 4 + (threadIdx.x >> 6);
  if (n >= N) return;
  const int beg = rowptr[n], end = rowptr[n + 1];
  unsigned int u = X[(size_t)n * 64 + lane];
  float s0 = b2f((unsigned short)u), s1 = b2f((unsigned short)(u >> 16));
  float t0 = 0.f, t1 = 0.f, p0 = 0.f, p1 = 0.f, q0 = 0.f, q1 = 0.f;
  int j = beg;
  for (; j + 4 <= end; j += 4) {
    int c0 = col[j], c1 = col[j + 1], c2 = col[j + 2], c3 = col[j + 3];
    unsigned int u0 = X[(size_t)c0 * 64 + lane];
    unsigned int u1 = X[(size_t)c1 * 64 + lane];
    unsigned int u2 = X[(size_t)c2 * 64 + lane];
    unsigned int u3 = X[(size_t)c3 * 64 + lane];
    s0 += b2f((unsigned short)u0); s1 += b2f((unsigned short)(u0 >> 16));
    t0 += b2f((unsigned short)u1); t1 += b2f((unsigned short)(u1 >> 16));
    p0 += b2f((unsigned short)u2); p1 += b2f((unsigned short)(u2 >> 16));
    q0 += b2f((unsigned short)u3); q1 += b2f((unsigned short)(u3 >> 16));
  }
  for (; j < end; ++j) {
    unsigned int uu = X[(size_t)col[j] * 64 + lane];
    s0 += b2f((unsigned short)uu); s1 += b2f((unsigned short)(uu >> 16));
  }
  float r0 = s0 + t0 + p0 + q0, r1 = s1 + t1 + p1 + q1;
  out[(size_t)n * 64 + lane] = (unsigned int)f2b(r0) | ((unsigned int)f2b(r1) << 16);
}

// --- bf16 MFMA GEMM: out[n][fo] = act(A[n]@W + b). Block: 4 waves x 16 nodes.
// Wt (B^T, bf16 [FoPad][Fi]) staged in LDS with XOR swizzle; A-frags from global.
template<int Fi, int FoPad, bool RELU>
__global__ __launch_bounds__(256) void gemm_mfma(
    const unsigned short* __restrict__ A, const unsigned short* __restrict__ WtG,
    const float* __restrict__ bias, unsigned short* __restrict__ out,
    int N, int Fo) {
  __shared__ unsigned short Wlds[FoPad * Fi];
  const int t = threadIdx.x;
  const int n0 = blockIdx.x * 64;

  // stage Wt -> LDS, 16B chunks, byte ^= (row&7)<<4
  constexpr int NCH = FoPad * Fi / 8;       // 16B chunks
  constexpr int CPR = Fi / 8;               // chunks per row
  for (int c = t; c < NCH; c += 256) {
    int row = c / CPR;
    uint4 v = ((const uint4*)WtG)[c];
    int boff = (c * 16) ^ ((row & 7) << 4);
    *(uint4*)((char*)Wlds + boff) = v;
  }
  __syncthreads();

  const int l = t & 63, w = t >> 6;
  const int kgrp = l >> 4;                  // 0..3
  const int rc = l & 15;
  int arow = n0 + w * 16 + rc;
  int arowc = arow < N ? arow : N - 1;

  constexpr int NF = FoPad / 16;
  f32x4 acc[NF];
#pragma unroll
  for (int nf = 0; nf < NF; ++nf) acc[nf] = (f32x4){0.f, 0.f, 0.f, 0.f};

#pragma unroll
  for (int k0 = 0; k0 < Fi; k0 += 32) {
    bf16x8 a = *(const bf16x8*)(A + (size_t)arowc * Fi + k0 + kgrp * 8);
#pragma unroll
    for (int nf = 0; nf < NF; ++nf) {
      int frow = nf * 16 + rc;
      int boff = ((frow * Fi + k0 + kgrp * 8) * 2) ^ ((frow & 7) << 4);
      bf16x8 b = *(const bf16x8*)((const char*)Wlds + boff);
      acc[nf] = __builtin_amdgcn_mfma_f32_16x16x32_bf16(a, b, acc[nf], 0, 0, 0);
    }
  }

#pragma unroll
  for (int nf = 0; nf < NF; ++nf) {
    int fo = nf * 16 + rc;
    float bs = (fo < Fo) ? bias[fo] : 0.f;
#pragma unroll
    for (int q = 0; q < 4; ++q) {
      int n = n0 + w * 16 + kgrp * 4 + q;
      if (n < N && fo < Fo) {
        float v = acc[nf][q] + bs;
        if (RELU) v = fmaxf(v, 0.f);
        out[(size_t)n * Fo + fo] = f2b(v);
      }
    }
  }
}

// --- final 40x40 GEMM + row log-softmax, one wave per node. A is bf16 [N,40].
__global__ __launch_bounds__(256) void gemm_lsm_kernel(
    const unsigned short* __restrict__ A, const float* __restrict__ W,
    const float* __restrict__ bias, float* __restrict__ out, int N) {
  __shared__ float Wl[40 * 40];
  __shared__ float bl[40];
  int t = threadIdx.x;
  for (int i = t; i < 1600; i += 256) Wl[i] = W[i];
  if (t < 40) bl[t] = bias[t];
  __syncthreads();

  const int lane = t & 63;
  const int wid  = blockIdx.x * 4 + (t >> 6);
  const int nw   = gridDim.x * 4;
  for (int n = wid; n < N; n += nw) {
    const unsigned short* a = A + (size_t)n * 40;
    float acc = (lane < 40) ? bl[lane] : 0.f;
    if (lane < 40) {
#pragma unroll 8
      for (int k = 0; k < 40; ++k)
        acc += b2f(a[k]) * Wl[k * 40 + lane];
    }
    float m = (lane < 40) ? acc : -3.4e38f;
#pragma unroll
    for (int o = 32; o >= 1; o >>= 1) m = fmaxf(m, __shfl_xor(m, o, 64));
    float ex = (lane < 40) ? expf(acc - m) : 0.f;
    float ssum = ex;
#pragma unroll
    for (int o = 32; o >= 1; o >>= 1) ssum += __shfl_xor(ssum, o, 64);
    if (lane < 40) out[(size_t)n * 40 + lane] = acc - m - logf(ssum);
  }
}

extern "C" void kernel_launch(void* const* d_in, const int* in_sizes, int n_in,
                              void* d_out, int out_size, void* d_ws, size_t ws_size,
                              hipStream_t stream) {
  const float*        x   = (const float*)d_in[0];
  const unsigned int* ew  = (const unsigned int*)d_in[1];
  const float*        W1a = (const float*)d_in[2];
  const float*        b1a = (const float*)d_in[3];
  const float*        W2a = (const float*)d_in[4];
  const float*        b2a = (const float*)d_in[5];
  const float*        W1b = (const float*)d_in[6];
  const float*        b1b = (const float*)d_in[7];
  const float*        W2b = (const float*)d_in[8];
  const float*        b2b = (const float*)d_in[9];

  const int N = in_sizes[0] / 64;     // 100000
  const int E = in_sizes[1] / 2;      // 1200000
  float* out = (float*)d_out;

  char* ws = (char*)d_ws;
  size_t off = 0;
  auto alloc = [&](size_t bytes) {
    char* p = ws + off;
    off += (bytes + WS_ALIGN - 1) & ~(size_t)(WS_ALIGN - 1);
    return p;
  };
  unsigned int*  flag   = (unsigned int*)alloc(4);
  int*           rowptr = (int*)alloc((size_t)(N + 2) * 4);
  int*           wptr   = (int*)alloc((size_t)N * 4);
  int*           bsum   = (int*)alloc(160 * 4);
  int*           col    = (int*)alloc((size_t)E * 4);
  unsigned short* Wt1   = (unsigned short*)alloc((size_t)128 * 64 * 2);
  unsigned short* Wt2   = (unsigned short*)alloc((size_t)128 * 128 * 2);
  unsigned short* Wt3   = (unsigned short*)alloc((size_t)48 * 128 * 2);
  unsigned short* xa    = (unsigned short*)alloc((size_t)N * 64 * 2);
  unsigned short* mid   = (unsigned short*)alloc((size_t)N * 128 * 2);
  unsigned short* h     = (unsigned short*)alloc((size_t)N * 128 * 2);
  unsigned short* ha    = (unsigned short*)alloc((size_t)N * 128 * 2);
  unsigned short* mid2  = (unsigned short*)alloc((size_t)N * 40 * 2);

  const int nb = (N + SCAN_E - 1) / SCAN_E;

  hipMemsetAsync(flag, 0, 4, stream);
  sniff_kernel<<<1, 256, 0, stream>>>(ew, flag, E);

  // CSR build
  hipMemsetAsync(rowptr, 0, (size_t)(N + 1) * sizeof(int), stream);
  hist_kernel<<<2048, 256, 0, stream>>>(ew, flag, rowptr, E);
  scan1_kernel<<<nb, SCAN_T, 0, stream>>>(rowptr, bsum, N);
  scan2_kernel<<<1, 64, 0, stream>>>(bsum, nb);
  scan3_kernel<<<nb, SCAN_T, 0, stream>>>(rowptr, wptr, bsum, N, E);
  fill_kernel<<<2048, 256, 0, stream>>>(ew, flag, wptr, col, E);

  // weight transposes (bf16)
  transw_kernel<<<(128 * 64 + 255) / 256, 256, 0, stream>>>(W1a, Wt1, 64, 128, 128);
  transw_kernel<<<(128 * 128 + 255) / 256, 256, 0, stream>>>(W2a, Wt2, 128, 128, 128);
  transw_kernel<<<(48 * 128 + 255) / 256, 256, 0, stream>>>(W1b, Wt3, 128, 40, 48);

  const int gGather = (N + 3) / 4;
  const int gGemm = (N + 63) / 64;

  // conv1
  gather64_kernel<<<gGather, 256, 0, stream>>>(x, rowptr, col, xa, N);
  gemm_mfma<64, 128, true><<<gGemm, 256, 0, stream>>>(xa, Wt1, b1a, mid, N, 128);
  gemm_mfma<128, 128, true><<<gGemm, 256, 0, stream>>>(mid, Wt2, b2a, h, N, 128);

  // conv2
  gather128_kernel<<<gGather, 256, 0, stream>>>((const unsigned int*)h, rowptr, col,
                                                (unsigned int*)ha, N);
  gemm_mfma<128, 48, true><<<gGemm, 256, 0, stream>>>(ha, Wt3, b1b, mid2, N, 40);
  gemm_lsm_kernel<<<1024, 256, 0, stream>>>(mid2, W2b, b2b, out, N);
}

// Round 4
// 337.125 us; speedup vs baseline: 3.2841x; 1.1361x over previous
//
#include <hip/hip_runtime.h>
#include <hip/hip_bf16.h>
#include <math.h>

// ---------------------------------------------------------------------------
// GIN 2-layer forward. CSR via two-level counting sort (no global atomics),
// CSR-gather aggregation (f32 sums), bf16 MFMA GEMMs.
//   xa = x + seg_sum(x[src],dst); mid = relu(xa@W1a+b1a); h = relu(mid@W2a+b2a)
//   ha = h + seg_sum(h[src],dst); mid2 = relu(ha@W1b+b1b)
//   out = log_softmax(mid2@W2b+b2b)
// N=100000, E=1200000, IN=64, HID=128, OUT=40.
// ---------------------------------------------------------------------------

#define WS_ALIGN 256
#define NBLK_C 256          // edge-chunk blocks for bucket sort
#define NPB_SHIFT 9         // 512 nodes per coarse bucket
#define NPB 512

typedef __attribute__((ext_vector_type(8))) __bf16 bf16x8;
typedef __attribute__((ext_vector_type(4))) float f32x4;

__device__ inline unsigned short f2b(float f) {      // RNE f32->bf16
  unsigned int x = __float_as_uint(f);
  return (unsigned short)((x + 0x7fffu + ((x >> 16) & 1u)) >> 16);
}
__device__ inline float b2f(unsigned short u) {
  return __uint_as_float(((unsigned int)u) << 16);
}

// --- dtype sniff: edge_index may be int64 (ref) or int32 (x64-disabled JAX).
__global__ __launch_bounds__(256) void sniff_kernel(const unsigned int* __restrict__ ew,
                                                    unsigned int* __restrict__ flag, int E) {
  unsigned int acc = 0;
  int i = threadIdx.x;
  for (int j = 0; j < 16; ++j) {
    long long s = ((long long)(i * 16 + j) * 292 + 7) % E;
    acc |= ew[2 * (size_t)s + 1];
  }
  if (acc) atomicOr(flag, 1u);   // nonzero -> int32 layout
}

// --- K1: per-chunk coarse histogram. gcount[b*NBLK_C + blk] = #edges of chunk
// blk with dst in bucket b.
__global__ __launch_bounds__(256) void bhist_kernel(
    const unsigned int* __restrict__ ew, const unsigned int* __restrict__ flag,
    int* __restrict__ gcount, int E, int NB) {
  extern __shared__ int hist[];
  const bool is64 = (*flag == 0u);
  const int t = threadIdx.x, blk = blockIdx.x;
  for (int i = t; i < NB; i += 256) hist[i] = 0;
  __syncthreads();
  const int chunk = (E + NBLK_C - 1) / NBLK_C;
  const int beg = blk * chunk, end = min(E, beg + chunk);
  for (int e = beg + t; e < end; e += 256) {
    int d = is64 ? (int)ew[2 * (size_t)(E + e)] : (int)ew[(size_t)E + e];
    atomicAdd(&hist[d >> NPB_SHIFT], 1);
  }
  __syncthreads();
  for (int i = t; i < NB; i += 256) gcount[i * NBLK_C + blk] = hist[i];
}

// --- K2: single-block exclusive scan of gcount[NB*NBLK_C] in place.
__global__ __launch_bounds__(256) void bscan_kernel(int* __restrict__ g, int tot) {
  __shared__ int part[256];
  const int t = threadIdx.x;
  const int seg = (tot + 255) / 256;
  const int beg = t * seg, end = min(tot, beg + seg);
  int s = 0;
  for (int i = beg; i < end; ++i) s += g[i];
  part[t] = s;
  __syncthreads();
  for (int off = 1; off < 256; off <<= 1) {
    int u = (t >= off) ? part[t - off] : 0;
    __syncthreads();
    part[t] += u;
    __syncthreads();
  }
  int run = part[t] - s;
  for (int i = beg; i < end; ++i) { int v = g[i]; g[i] = run; run += v; }
}

// --- K3: scatter (src,dst) pairs bucket-major using LDS cursors.
__global__ __launch_bounds__(256) void bscatter_kernel(
    const unsigned int* __restrict__ ew, const unsigned int* __restrict__ flag,
    const int* __restrict__ gscan, uint2* __restrict__ pairs, int E, int NB) {
  extern __shared__ int cur[];
  const bool is64 = (*flag == 0u);
  const int t = threadIdx.x, blk = blockIdx.x;
  for (int i = t; i < NB; i += 256) cur[i] = gscan[i * NBLK_C + blk];
  __syncthreads();
  const int chunk = (E + NBLK_C - 1) / NBLK_C;
  const int beg = blk * chunk, end = min(E, beg + chunk);
  for (int e = beg + t; e < end; e += 256) {
    unsigned int s, d;
    if (is64) { s = ew[2 * (size_t)e]; d = ew[2 * (size_t)(E + e)]; }
    else      { s = ew[(size_t)e];     d = ew[(size_t)E + e]; }
    int pos = atomicAdd(&cur[d >> NPB_SHIFT], 1);
    pairs[pos] = make_uint2(s, d);
  }
}

// --- K4: per-bucket LDS counting sort -> rowptr (direct) + dense col writes.
__global__ __launch_bounds__(256) void bsort_kernel(
    const uint2* __restrict__ pairs, const int* __restrict__ gscan,
    int* __restrict__ rowptr, int* __restrict__ col, int E, int N, int NB) {
  __shared__ int cnt[NPB];
  __shared__ int scn[NPB];
  __shared__ int cur[NPB];
  __shared__ int part[256];
  const int t = threadIdx.x, b = blockIdx.x;
  const int base = gscan[(size_t)b * NBLK_C];
  const int bend = (b + 1 < NB) ? gscan[(size_t)(b + 1) * NBLK_C] : E;
  const int n0 = b << NPB_SHIFT;

  cnt[2 * t] = 0; cnt[2 * t + 1] = 0;
  __syncthreads();
  for (int j = base + t; j < bend; j += 256)
    atomicAdd(&cnt[pairs[j].y - n0], 1);
  __syncthreads();

  int c0 = cnt[2 * t], c1 = cnt[2 * t + 1];
  part[t] = c0 + c1;
  __syncthreads();
  for (int off = 1; off < 256; off <<= 1) {
    int u = (t >= off) ? part[t - off] : 0;
    __syncthreads();
    part[t] += u;
    __syncthreads();
  }
  int exc = part[t] - (c0 + c1);
  scn[2 * t] = exc; scn[2 * t + 1] = exc + c0;
  cur[2 * t] = base + exc; cur[2 * t + 1] = base + exc + c0;

  int g0 = n0 + 2 * t, g1 = n0 + 2 * t + 1;
  if (g0 < N) rowptr[g0] = base + scn[2 * t];
  if (g1 < N) rowptr[g1] = base + scn[2 * t + 1];
  if (b == NB - 1 && t == 0) rowptr[N] = E;
  __syncthreads();

  for (int j = base + t; j < bend; j += 256) {
    uint2 p = pairs[j];
    int pos = atomicAdd(&cur[p.y - n0], 1);
    col[pos] = (int)p.x;
  }
}

// --- weight transpose + cast: Wt[fo][k] = bf16(W[k][fo]), zero-pad fo>=Fo
__global__ __launch_bounds__(256) void transw_kernel(
    const float* __restrict__ W, unsigned short* __restrict__ Wt,
    int Fi, int Fo, int FoPad) {
  int i = blockIdx.x * 256 + threadIdx.x;
  if (i >= FoPad * Fi) return;
  int fo = i / Fi, k = i - fo * Fi;
  float v = (fo < Fo) ? W[(size_t)k * Fo + fo] : 0.f;
  Wt[i] = f2b(v);
}

// --- gather conv1: out_bf16[n] = x[n] + sum_{j} x[col[j]]   (x is f32 [N,64])
__global__ __launch_bounds__(256) void gather64_kernel(
    const float* __restrict__ X, const int* __restrict__ rowptr,
    const int* __restrict__ col, unsigned short* __restrict__ out, int N) {
  const int lane = threadIdx.x & 63;
  const int n = blockIdx.x * 4 + (threadIdx.x >> 6);
  if (n >= N) return;
  const int beg = rowptr[n], end = rowptr[n + 1];
  float a0 = X[(size_t)n * 64 + lane], a1 = 0.f, a2 = 0.f, a3 = 0.f;
  int j = beg;
  for (; j + 4 <= end; j += 4) {
    int c0 = col[j], c1 = col[j + 1], c2 = col[j + 2], c3 = col[j + 3];
    a0 += X[(size_t)c0 * 64 + lane];
    a1 += X[(size_t)c1 * 64 + lane];
    a2 += X[(size_t)c2 * 64 + lane];
    a3 += X[(size_t)c3 * 64 + lane];
  }
  for (; j < end; ++j) a0 += X[(size_t)col[j] * 64 + lane];
  out[(size_t)n * 64 + lane] = f2b(a0 + a1 + a2 + a3);
}

// --- gather conv2: bf16 [N,128] in/out, f32 sums; lane handles 2 features.
__global__ __launch_bounds__(256) void gather128_kernel(
    const unsigned int* __restrict__ X, const int* __restrict__ rowptr,
    const int* __restrict__ col, unsigned int* __restrict__ out, int N) {
  const int lane = threadIdx.x & 63;
  const int n = blockIdx.x * 4 + (threadIdx.x >> 6);
  if (n >= N) return;
  const int beg = rowptr[n], end = rowptr[n + 1];
  unsigned int u = X[(size_t)n * 64 + lane];
  float s0 = b2f((unsigned short)u), s1 = b2f((unsigned short)(u >> 16));
  float t0 = 0.f, t1 = 0.f, p0 = 0.f, p1 = 0.f, q0 = 0.f, q1 = 0.f;
  int j = beg;
  for (; j + 4 <= end; j += 4) {
    int c0 = col[j], c1 = col[j + 1], c2 = col[j + 2], c3 = col[j + 3];
    unsigned int u0 = X[(size_t)c0 * 64 + lane];
    unsigned int u1 = X[(size_t)c1 * 64 + lane];
    unsigned int u2 = X[(size_t)c2 * 64 + lane];
    unsigned int u3 = X[(size_t)c3 * 64 + lane];
    s0 += b2f((unsigned short)u0); s1 += b2f((unsigned short)(u0 >> 16));
    t0 += b2f((unsigned short)u1); t1 += b2f((unsigned short)(u1 >> 16));
    p0 += b2f((unsigned short)u2); p1 += b2f((unsigned short)(u2 >> 16));
    q0 += b2f((unsigned short)u3); q1 += b2f((unsigned short)(u3 >> 16));
  }
  for (; j < end; ++j) {
    unsigned int uu = X[(size_t)col[j] * 64 + lane];
    s0 += b2f((unsigned short)uu); s1 += b2f((unsigned short)(uu >> 16));
  }
  float r0 = s0 + t0 + p0 + q0, r1 = s1 + t1 + p1 + q1;
  out[(size_t)n * 64 + lane] = (unsigned int)f2b(r0) | ((unsigned int)f2b(r1) << 16);
}

// --- bf16 MFMA GEMM: out[n][fo] = act(A[n]@W + b). Block: 4 waves x 16 nodes.
// Wt (B^T, bf16 [FoPad][Fi]) staged in LDS with XOR swizzle; A-frags from global.
template<int Fi, int FoPad, bool RELU>
__global__ __launch_bounds__(256) void gemm_mfma(
    const unsigned short* __restrict__ A, const unsigned short* __restrict__ WtG,
    const float* __restrict__ bias, unsigned short* __restrict__ out,
    int N, int Fo) {
  __shared__ unsigned short Wlds[FoPad * Fi];
  const int t = threadIdx.x;
  const int n0 = blockIdx.x * 64;

  constexpr int NCH = FoPad * Fi / 8;       // 16B chunks
  constexpr int CPR = Fi / 8;               // chunks per row
  for (int c = t; c < NCH; c += 256) {
    int row = c / CPR;
    uint4 v = ((const uint4*)WtG)[c];
    int boff = (c * 16) ^ ((row & 7) << 4);
    *(uint4*)((char*)Wlds + boff) = v;
  }
  __syncthreads();

  const int l = t & 63, w = t >> 6;
  const int kgrp = l >> 4;                  // 0..3
  const int rc = l & 15;
  int arow = n0 + w * 16 + rc;
  int arowc = arow < N ? arow : N - 1;

  constexpr int NF = FoPad / 16;
  f32x4 acc[NF];
#pragma unroll
  for (int nf = 0; nf < NF; ++nf) acc[nf] = (f32x4){0.f, 0.f, 0.f, 0.f};

#pragma unroll
  for (int k0 = 0; k0 < Fi; k0 += 32) {
    bf16x8 a = *(const bf16x8*)(A + (size_t)arowc * Fi + k0 + kgrp * 8);
#pragma unroll
    for (int nf = 0; nf < NF; ++nf) {
      int frow = nf * 16 + rc;
      int boff = ((frow * Fi + k0 + kgrp * 8) * 2) ^ ((frow & 7) << 4);
      bf16x8 b = *(const bf16x8*)((const char*)Wlds + boff);
      acc[nf] = __builtin_amdgcn_mfma_f32_16x16x32_bf16(a, b, acc[nf], 0, 0, 0);
    }
  }

#pragma unroll
  for (int nf = 0; nf < NF; ++nf) {
    int fo = nf * 16 + rc;
    float bs = (fo < Fo) ? bias[fo] : 0.f;
#pragma unroll
    for (int q = 0; q < 4; ++q) {
      int n = n0 + w * 16 + kgrp * 4 + q;
      if (n < N && fo < Fo) {
        float v = acc[nf][q] + bs;
        if (RELU) v = fmaxf(v, 0.f);
        out[(size_t)n * Fo + fo] = f2b(v);
      }
    }
  }
}

// --- final 40x40 GEMM + row log-softmax, one wave per node. A is bf16 [N,40].
__global__ __launch_bounds__(256) void gemm_lsm_kernel(
    const unsigned short* __restrict__ A, const float* __restrict__ W,
    const float* __restrict__ bias, float* __restrict__ out, int N) {
  __shared__ float Wl[40 * 40];
  __shared__ float bl[40];
  int t = threadIdx.x;
  for (int i = t; i < 1600; i += 256) Wl[i] = W[i];
  if (t < 40) bl[t] = bias[t];
  __syncthreads();

  const int lane = t & 63;
  const int wid  = blockIdx.x * 4 + (t >> 6);
  const int nw   = gridDim.x * 4;
  for (int n = wid; n < N; n += nw) {
    const unsigned short* a = A + (size_t)n * 40;
    float acc = (lane < 40) ? bl[lane] : 0.f;
    if (lane < 40) {
#pragma unroll 8
      for (int k = 0; k < 40; ++k)
        acc += b2f(a[k]) * Wl[k * 40 + lane];
    }
    float m = (lane < 40) ? acc : -3.4e38f;
#pragma unroll
    for (int o = 32; o >= 1; o >>= 1) m = fmaxf(m, __shfl_xor(m, o, 64));
    float ex = (lane < 40) ? expf(acc - m) : 0.f;
    float ssum = ex;
#pragma unroll
    for (int o = 32; o >= 1; o >>= 1) ssum += __shfl_xor(ssum, o, 64);
    if (lane < 40) out[(size_t)n * 40 + lane] = acc - m - logf(ssum);
  }
}

extern "C" void kernel_launch(void* const* d_in, const int* in_sizes, int n_in,
                              void* d_out, int out_size, void* d_ws, size_t ws_size,
                              hipStream_t stream) {
  const float*        x   = (const float*)d_in[0];
  const unsigned int* ew  = (const unsigned int*)d_in[1];
  const float*        W1a = (const float*)d_in[2];
  const float*        b1a = (const float*)d_in[3];
  const float*        W2a = (const float*)d_in[4];
  const float*        b2a = (const float*)d_in[5];
  const float*        W1b = (const float*)d_in[6];
  const float*        b1b = (const float*)d_in[7];
  const float*        W2b = (const float*)d_in[8];
  const float*        b2b = (const float*)d_in[9];

  const int N = in_sizes[0] / 64;     // 100000
  const int E = in_sizes[1] / 2;      // 1200000
  const int NB = (N + NPB - 1) >> NPB_SHIFT;   // coarse buckets (196)
  float* out = (float*)d_out;

  char* ws = (char*)d_ws;
  size_t off = 0;
  auto alloc = [&](size_t bytes) {
    char* p = ws + off;
    off += (bytes + WS_ALIGN - 1) & ~(size_t)(WS_ALIGN - 1);
    return p;
  };
  unsigned int*  flag   = (unsigned int*)alloc(4);
  int*           rowptr = (int*)alloc((size_t)(N + 2) * 4);
  int*           gscan  = (int*)alloc((size_t)NB * NBLK_C * 4);
  int*           col    = (int*)alloc((size_t)E * 4);
  unsigned short* Wt1   = (unsigned short*)alloc((size_t)128 * 64 * 2);
  unsigned short* Wt2   = (unsigned short*)alloc((size_t)128 * 128 * 2);
  unsigned short* Wt3   = (unsigned short*)alloc((size_t)48 * 128 * 2);
  unsigned short* xa    = (unsigned short*)alloc((size_t)N * 64 * 2);
  unsigned short* mid   = (unsigned short*)alloc((size_t)N * 128 * 2);
  unsigned short* h     = (unsigned short*)alloc((size_t)N * 128 * 2);
  unsigned short* ha    = (unsigned short*)alloc((size_t)N * 128 * 2);
  unsigned short* mid2  = (unsigned short*)alloc((size_t)N * 40 * 2);
  // pairs staging (9.6 MB) aliases `mid` (25.6 MB) — only live during CSR build
  uint2* pairs = (uint2*)mid;

  hipMemsetAsync(flag, 0, 4, stream);
  sniff_kernel<<<1, 256, 0, stream>>>(ew, flag, E);

  // --- CSR build: two-level counting sort
  const size_t ldsNB = (size_t)NB * 4;
  bhist_kernel<<<NBLK_C, 256, ldsNB, stream>>>(ew, flag, gscan, E, NB);
  bscan_kernel<<<1, 256, 0, stream>>>(gscan, NB * NBLK_C);
  bscatter_kernel<<<NBLK_C, 256, ldsNB, stream>>>(ew, flag, gscan, pairs, E, NB);
  bsort_kernel<<<NB, 256, 0, stream>>>(pairs, gscan, rowptr, col, E, N, NB);

  // weight transposes (bf16)
  transw_kernel<<<(128 * 64 + 255) / 256, 256, 0, stream>>>(W1a, Wt1, 64, 128, 128);
  transw_kernel<<<(128 * 128 + 255) / 256, 256, 0, stream>>>(W2a, Wt2, 128, 128, 128);
  transw_kernel<<<(48 * 128 + 255) / 256, 256, 0, stream>>>(W1b, Wt3, 128, 40, 48);

  const int gGather = (N + 3) / 4;
  const int gGemm = (N + 63) / 64;

  // conv1
  gather64_kernel<<<gGather, 256, 0, stream>>>(x, rowptr, col, xa, N);
  gemm_mfma<64, 128, true><<<gGemm, 256, 0, stream>>>(xa, Wt1, b1a, mid, N, 128);
  gemm_mfma<128, 128, true><<<gGemm, 256, 0, stream>>>(mid, Wt2, b2a, h, N, 128);

  // conv2
  gather128_kernel<<<gGather, 256, 0, stream>>>((const unsigned int*)h, rowptr, col,
                                                (unsigned int*)ha, N);
  gemm_mfma<128, 48, true><<<gGemm, 256, 0, stream>>>(ha, Wt3, b1b, mid2, N, 40);
  gemm_lsm_kernel<<<1024, 256, 0, stream>>>(mid2, W2b, b2b, out, N);
}

// Round 5
// 266.261 us; speedup vs baseline: 4.1581x; 1.2661x over previous
//
#include <hip/hip_runtime.h>
#include <hip/hip_bf16.h>
#include <math.h>

// ---------------------------------------------------------------------------
// GIN 2-layer forward. CSR via two-level counting sort (no global atomics),
// CSR-gather aggregation (f32 sums), bf16 MFMA GEMMs.
//   xa = x + seg_sum(x[src],dst); mid = relu(xa@W1a+b1a); h = relu(mid@W2a+b2a)
//   ha = h + seg_sum(h[src],dst); mid2 = relu(ha@W1b+b1b)
//   out = log_softmax(mid2@W2b+b2b)
// N=100000, E=1200000, IN=64, HID=128, OUT=40.
// ---------------------------------------------------------------------------

#define WS_ALIGN 256
#define NBLK_C 256          // edge-chunk blocks for bucket sort
#define NPB_SHIFT 9         // 512 nodes per coarse bucket
#define NPB 512
#define SCAN_T 256
#define SCAN_E 1024         // elements per scan block

typedef __attribute__((ext_vector_type(8))) __bf16 bf16x8;
typedef __attribute__((ext_vector_type(4))) float f32x4;

__device__ inline unsigned short f2b(float f) {      // RNE f32->bf16
  unsigned int x = __float_as_uint(f);
  return (unsigned short)((x + 0x7fffu + ((x >> 16) & 1u)) >> 16);
}
__device__ inline float b2f(unsigned short u) {
  return __uint_as_float(((unsigned int)u) << 16);
}

// --- dtype sniff: edge_index may be int64 (ref) or int32 (x64-disabled JAX).
__global__ __launch_bounds__(256) void sniff_kernel(const unsigned int* __restrict__ ew,
                                                    unsigned int* __restrict__ flag, int E) {
  unsigned int acc = 0;
  int i = threadIdx.x;
  for (int j = 0; j < 16; ++j) {
    long long s = ((long long)(i * 16 + j) * 292 + 7) % E;
    acc |= ew[2 * (size_t)s + 1];
  }
  if (acc) atomicOr(flag, 1u);   // nonzero -> int32 layout
}

// --- K1: per-chunk coarse histogram. gcount[b*NBLK_C + blk] = #edges of chunk
// blk with dst in bucket b.
__global__ __launch_bounds__(256) void bhist_kernel(
    const unsigned int* __restrict__ ew, const unsigned int* __restrict__ flag,
    int* __restrict__ gcount, int E, int NB) {
  extern __shared__ int hist[];
  const bool is64 = (*flag == 0u);
  const int t = threadIdx.x, blk = blockIdx.x;
  for (int i = t; i < NB; i += 256) hist[i] = 0;
  __syncthreads();
  const int chunk = (E + NBLK_C - 1) / NBLK_C;
  const int beg = blk * chunk, end = min(E, beg + chunk);
  for (int e = beg + t; e < end; e += 256) {
    int d = is64 ? (int)ew[2 * (size_t)(E + e)] : (int)ew[(size_t)E + e];
    atomicAdd(&hist[d >> NPB_SHIFT], 1);
  }
  __syncthreads();
  for (int i = t; i < NB; i += 256) gcount[i * NBLK_C + blk] = hist[i];
}

// --- K2: 3-pass parallel exclusive scan of gcount[tot] in place.
__global__ __launch_bounds__(SCAN_T) void pscan1_kernel(const int* __restrict__ g,
                                                        int* __restrict__ bsum, int tot) {
  __shared__ int s[SCAN_T];
  int b = blockIdx.x, t = threadIdx.x;
  int base = b * SCAN_E + t * 4;
  int v = 0;
#pragma unroll
  for (int k = 0; k < 4; ++k) { int i = base + k; if (i < tot) v += g[i]; }
  s[t] = v; __syncthreads();
  for (int off = SCAN_T / 2; off >= 1; off >>= 1) {
    if (t < off) s[t] += s[t + off];
    __syncthreads();
  }
  if (t == 0) bsum[b] = s[0];
}

__global__ void pscan2_kernel(int* __restrict__ bsum, int nb) {
  if (blockIdx.x == 0 && threadIdx.x == 0) {
    int run = 0;
    for (int i = 0; i < nb; ++i) { int v = bsum[i]; bsum[i] = run; run += v; }
    bsum[nb] = run;
  }
}

__global__ __launch_bounds__(SCAN_T) void pscan3_kernel(
    int* __restrict__ g, const int* __restrict__ bsum, int tot) {
  __shared__ int s[SCAN_T];
  int b = blockIdx.x, t = threadIdx.x;
  int base = b * SCAN_E + t * 4;
  int d[4]; int v = 0;
#pragma unroll
  for (int k = 0; k < 4; ++k) { int i = base + k; d[k] = (i < tot) ? g[i] : 0; v += d[k]; }
  s[t] = v; __syncthreads();
  for (int off = 1; off < SCAN_T; off <<= 1) {
    int u = (t >= off) ? s[t - off] : 0;
    __syncthreads();
    s[t] += u;
    __syncthreads();
  }
  int exc = s[t] - v + bsum[b];
#pragma unroll
  for (int k = 0; k < 4; ++k) {
    int i = base + k;
    if (i < tot) { g[i] = exc; exc += d[k]; }
  }
}

// --- K3: scatter (src,dst) pairs bucket-major using LDS cursors.
__global__ __launch_bounds__(256) void bscatter_kernel(
    const unsigned int* __restrict__ ew, const unsigned int* __restrict__ flag,
    const int* __restrict__ gscan, uint2* __restrict__ pairs, int E, int NB) {
  extern __shared__ int cur[];
  const bool is64 = (*flag == 0u);
  const int t = threadIdx.x, blk = blockIdx.x;
  for (int i = t; i < NB; i += 256) cur[i] = gscan[i * NBLK_C + blk];
  __syncthreads();
  const int chunk = (E + NBLK_C - 1) / NBLK_C;
  const int beg = blk * chunk, end = min(E, beg + chunk);
  for (int e = beg + t; e < end; e += 256) {
    unsigned int s, d;
    if (is64) { s = ew[2 * (size_t)e]; d = ew[2 * (size_t)(E + e)]; }
    else      { s = ew[(size_t)e];     d = ew[(size_t)E + e]; }
    int pos = atomicAdd(&cur[d >> NPB_SHIFT], 1);
    pairs[pos] = make_uint2(s, d);
  }
}

// --- K4: per-bucket LDS counting sort -> rowptr (direct) + dense col writes.
__global__ __launch_bounds__(256) void bsort_kernel(
    const uint2* __restrict__ pairs, const int* __restrict__ gscan,
    int* __restrict__ rowptr, int* __restrict__ col, int E, int N, int NB) {
  __shared__ int cnt[NPB];
  __shared__ int scn[NPB];
  __shared__ int cur[NPB];
  __shared__ int part[256];
  const int t = threadIdx.x, b = blockIdx.x;
  const int base = gscan[(size_t)b * NBLK_C];
  const int bend = (b + 1 < NB) ? gscan[(size_t)(b + 1) * NBLK_C] : E;
  const int n0 = b << NPB_SHIFT;

  cnt[2 * t] = 0; cnt[2 * t + 1] = 0;
  __syncthreads();
  for (int j = base + t; j < bend; j += 256)
    atomicAdd(&cnt[pairs[j].y - n0], 1);
  __syncthreads();

  int c0 = cnt[2 * t], c1 = cnt[2 * t + 1];
  part[t] = c0 + c1;
  __syncthreads();
  for (int off = 1; off < 256; off <<= 1) {
    int u = (t >= off) ? part[t - off] : 0;
    __syncthreads();
    part[t] += u;
    __syncthreads();
  }
  int exc = part[t] - (c0 + c1);
  scn[2 * t] = exc; scn[2 * t + 1] = exc + c0;
  cur[2 * t] = base + exc; cur[2 * t + 1] = base + exc + c0;

  int g0 = n0 + 2 * t, g1 = n0 + 2 * t + 1;
  if (g0 < N) rowptr[g0] = base + scn[2 * t];
  if (g1 < N) rowptr[g1] = base + scn[2 * t + 1];
  if (b == NB - 1 && t == 0) rowptr[N] = E;
  __syncthreads();

  for (int j = base + t; j < bend; j += 256) {
    uint2 p = pairs[j];
    int pos = atomicAdd(&cur[p.y - n0], 1);
    col[pos] = (int)p.x;
  }
}

// --- weight transpose + cast: Wt[fo][k] = bf16(W[k][fo]), zero-pad fo>=Fo
__global__ __launch_bounds__(256) void transw_kernel(
    const float* __restrict__ W, unsigned short* __restrict__ Wt,
    int Fi, int Fo, int FoPad) {
  int i = blockIdx.x * 256 + threadIdx.x;
  if (i >= FoPad * Fi) return;
  int fo = i / Fi, k = i - fo * Fi;
  float v = (fo < Fo) ? W[(size_t)k * Fo + fo] : 0.f;
  Wt[i] = f2b(v);
}

// --- gather conv1: out_bf16[n] = x[n] + sum_{j} x[col[j]]   (x is f32 [N,64])
__global__ __launch_bounds__(256) void gather64_kernel(
    const float* __restrict__ X, const int* __restrict__ rowptr,
    const int* __restrict__ col, unsigned short* __restrict__ out, int N) {
  const int lane = threadIdx.x & 63;
  const int n = blockIdx.x * 4 + (threadIdx.x >> 6);
  if (n >= N) return;
  const int beg = rowptr[n], end = rowptr[n + 1];
  float a0 = X[(size_t)n * 64 + lane], a1 = 0.f, a2 = 0.f, a3 = 0.f;
  int j = beg;
  for (; j + 4 <= end; j += 4) {
    int c0 = col[j], c1 = col[j + 1], c2 = col[j + 2], c3 = col[j + 3];
    a0 += X[(size_t)c0 * 64 + lane];
    a1 += X[(size_t)c1 * 64 + lane];
    a2 += X[(size_t)c2 * 64 + lane];
    a3 += X[(size_t)c3 * 64 + lane];
  }
  for (; j < end; ++j) a0 += X[(size_t)col[j] * 64 + lane];
  out[(size_t)n * 64 + lane] = f2b(a0 + a1 + a2 + a3);
}

// --- gather conv2: bf16 [N,128] in/out, f32 sums; lane handles 2 features.
__global__ __launch_bounds__(256) void gather128_kernel(
    const unsigned int* __restrict__ X, const int* __restrict__ rowptr,
    const int* __restrict__ col, unsigned int* __restrict__ out, int N) {
  const int lane = threadIdx.x & 63;
  const int n = blockIdx.x * 4 + (threadIdx.x >> 6);
  if (n >= N) return;
  const int beg = rowptr[n], end = rowptr[n + 1];
  unsigned int u = X[(size_t)n * 64 + lane];
  float s0 = b2f((unsigned short)u), s1 = b2f((unsigned short)(u >> 16));
  float t0 = 0.f, t1 = 0.f, p0 = 0.f, p1 = 0.f, q0 = 0.f, q1 = 0.f;
  int j = beg;
  for (; j + 4 <= end; j += 4) {
    int c0 = col[j], c1 = col[j + 1], c2 = col[j + 2], c3 = col[j + 3];
    unsigned int u0 = X[(size_t)c0 * 64 + lane];
    unsigned int u1 = X[(size_t)c1 * 64 + lane];
    unsigned int u2 = X[(size_t)c2 * 64 + lane];
    unsigned int u3 = X[(size_t)c3 * 64 + lane];
    s0 += b2f((unsigned short)u0); s1 += b2f((unsigned short)(u0 >> 16));
    t0 += b2f((unsigned short)u1); t1 += b2f((unsigned short)(u1 >> 16));
    p0 += b2f((unsigned short)u2); p1 += b2f((unsigned short)(u2 >> 16));
    q0 += b2f((unsigned short)u3); q1 += b2f((unsigned short)(u3 >> 16));
  }
  for (; j < end; ++j) {
    unsigned int uu = X[(size_t)col[j] * 64 + lane];
    s0 += b2f((unsigned short)uu); s1 += b2f((unsigned short)(uu >> 16));
  }
  float r0 = s0 + t0 + p0 + q0, r1 = s1 + t1 + p1 + q1;
  out[(size_t)n * 64 + lane] = (unsigned int)f2b(r0) | ((unsigned int)f2b(r1) << 16);
}

// --- bf16 MFMA GEMM: out[n][fo] = act(A[n]@W + b). Block: 4 waves x 16 nodes.
// Wt (B^T, bf16 [FoPad][Fi]) staged in LDS with XOR swizzle; A-frags from global.
template<int Fi, int FoPad, bool RELU>
__global__ __launch_bounds__(256) void gemm_mfma(
    const unsigned short* __restrict__ A, const unsigned short* __restrict__ WtG,
    const float* __restrict__ bias, unsigned short* __restrict__ out,
    int N, int Fo) {
  __shared__ unsigned short Wlds[FoPad * Fi];
  const int t = threadIdx.x;
  const int n0 = blockIdx.x * 64;

  constexpr int NCH = FoPad * Fi / 8;       // 16B chunks
  constexpr int CPR = Fi / 8;               // chunks per row
  for (int c = t; c < NCH; c += 256) {
    int row = c / CPR;
    uint4 v = ((const uint4*)WtG)[c];
    int boff = (c * 16) ^ ((row & 7) << 4);
    *(uint4*)((char*)Wlds + boff) = v;
  }
  __syncthreads();

  const int l = t & 63, w = t >> 6;
  const int kgrp = l >> 4;                  // 0..3
  const int rc = l & 15;
  int arow = n0 + w * 16 + rc;
  int arowc = arow < N ? arow : N - 1;

  constexpr int NF = FoPad / 16;
  f32x4 acc[NF];
#pragma unroll
  for (int nf = 0; nf < NF; ++nf) acc[nf] = (f32x4){0.f, 0.f, 0.f, 0.f};

#pragma unroll
  for (int k0 = 0; k0 < Fi; k0 += 32) {
    bf16x8 a = *(const bf16x8*)(A + (size_t)arowc * Fi + k0 + kgrp * 8);
#pragma unroll
    for (int nf = 0; nf < NF; ++nf) {
      int frow = nf * 16 + rc;
      int boff = ((frow * Fi + k0 + kgrp * 8) * 2) ^ ((frow & 7) << 4);
      bf16x8 b = *(const bf16x8*)((const char*)Wlds + boff);
      acc[nf] = __builtin_amdgcn_mfma_f32_16x16x32_bf16(a, b, acc[nf], 0, 0, 0);
    }
  }

#pragma unroll
  for (int nf = 0; nf < NF; ++nf) {
    int fo = nf * 16 + rc;
    float bs = (fo < Fo) ? bias[fo] : 0.f;
#pragma unroll
    for (int q = 0; q < 4; ++q) {
      int n = n0 + w * 16 + kgrp * 4 + q;
      if (n < N && fo < Fo) {
        float v = acc[nf][q] + bs;
        if (RELU) v = fmaxf(v, 0.f);
        out[(size_t)n * Fo + fo] = f2b(v);
      }
    }
  }
}

// --- final 40x40 GEMM + row log-softmax, one wave per node. A is bf16 [N,40].
__global__ __launch_bounds__(256) void gemm_lsm_kernel(
    const unsigned short* __restrict__ A, const float* __restrict__ W,
    const float* __restrict__ bias, float* __restrict__ out, int N) {
  __shared__ float Wl[40 * 40];
  __shared__ float bl[40];
  int t = threadIdx.x;
  for (int i = t; i < 1600; i += 256) Wl[i] = W[i];
  if (t < 40) bl[t] = bias[t];
  __syncthreads();

  const int lane = t & 63;
  const int wid  = blockIdx.x * 4 + (t >> 6);
  const int nw   = gridDim.x * 4;
  for (int n = wid; n < N; n += nw) {
    const unsigned short* a = A + (size_t)n * 40;
    float acc = (lane < 40) ? bl[lane] : 0.f;
    if (lane < 40) {
#pragma unroll 8
      for (int k = 0; k < 40; ++k)
        acc += b2f(a[k]) * Wl[k * 40 + lane];
    }
    float m = (lane < 40) ? acc : -3.4e38f;
#pragma unroll
    for (int o = 32; o >= 1; o >>= 1) m = fmaxf(m, __shfl_xor(m, o, 64));
    float ex = (lane < 40) ? expf(acc - m) : 0.f;
    float ssum = ex;
#pragma unroll
    for (int o = 32; o >= 1; o >>= 1) ssum += __shfl_xor(ssum, o, 64);
    if (lane < 40) out[(size_t)n * 40 + lane] = acc - m - logf(ssum);
  }
}

extern "C" void kernel_launch(void* const* d_in, const int* in_sizes, int n_in,
                              void* d_out, int out_size, void* d_ws, size_t ws_size,
                              hipStream_t stream) {
  const float*        x   = (const float*)d_in[0];
  const unsigned int* ew  = (const unsigned int*)d_in[1];
  const float*        W1a = (const float*)d_in[2];
  const float*        b1a = (const float*)d_in[3];
  const float*        W2a = (const float*)d_in[4];
  const float*        b2a = (const float*)d_in[5];
  const float*        W1b = (const float*)d_in[6];
  const float*        b1b = (const float*)d_in[7];
  const float*        W2b = (const float*)d_in[8];
  const float*        b2b = (const float*)d_in[9];

  const int N = in_sizes[0] / 64;     // 100000
  const int E = in_sizes[1] / 2;      // 1200000
  const int NB = (N + NPB - 1) >> NPB_SHIFT;   // coarse buckets (196)
  float* out = (float*)d_out;

  char* ws = (char*)d_ws;
  size_t off = 0;
  auto alloc = [&](size_t bytes) {
    char* p = ws + off;
    off += (bytes + WS_ALIGN - 1) & ~(size_t)(WS_ALIGN - 1);
    return p;
  };
  unsigned int*  flag   = (unsigned int*)alloc(4);
  int*           rowptr = (int*)alloc((size_t)(N + 2) * 4);
  int*           gscan  = (int*)alloc((size_t)NB * NBLK_C * 4);
  int*           bsum2  = (int*)alloc(256 * 4);
  int*           col    = (int*)alloc((size_t)E * 4);
  unsigned short* Wt1   = (unsigned short*)alloc((size_t)128 * 64 * 2);
  unsigned short* Wt2   = (unsigned short*)alloc((size_t)128 * 128 * 2);
  unsigned short* Wt3   = (unsigned short*)alloc((size_t)48 * 128 * 2);
  unsigned short* xa    = (unsigned short*)alloc((size_t)N * 64 * 2);
  unsigned short* mid   = (unsigned short*)alloc((size_t)N * 128 * 2);
  unsigned short* h     = (unsigned short*)alloc((size_t)N * 128 * 2);
  unsigned short* ha    = (unsigned short*)alloc((size_t)N * 128 * 2);
  unsigned short* mid2  = (unsigned short*)alloc((size_t)N * 40 * 2);
  // pairs staging (9.6 MB) aliases `mid` (25.6 MB) — only live during CSR build
  uint2* pairs = (uint2*)mid;

  hipMemsetAsync(flag, 0, 4, stream);
  sniff_kernel<<<1, 256, 0, stream>>>(ew, flag, E);

  // --- CSR build: two-level counting sort
  const size_t ldsNB = (size_t)NB * 4;
  const int tot = NB * NBLK_C;
  const int nb2 = (tot + SCAN_E - 1) / SCAN_E;
  bhist_kernel<<<NBLK_C, 256, ldsNB, stream>>>(ew, flag, gscan, E, NB);
  pscan1_kernel<<<nb2, SCAN_T, 0, stream>>>(gscan, bsum2, tot);
  pscan2_kernel<<<1, 64, 0, stream>>>(bsum2, nb2);
  pscan3_kernel<<<nb2, SCAN_T, 0, stream>>>(gscan, bsum2, tot);
  bscatter_kernel<<<NBLK_C, 256, ldsNB, stream>>>(ew, flag, gscan, pairs, E, NB);
  bsort_kernel<<<NB, 256, 0, stream>>>(pairs, gscan, rowptr, col, E, N, NB);

  // weight transposes (bf16)
  transw_kernel<<<(128 * 64 + 255) / 256, 256, 0, stream>>>(W1a, Wt1, 64, 128, 128);
  transw_kernel<<<(128 * 128 + 255) / 256, 256, 0, stream>>>(W2a, Wt2, 128, 128, 128);
  transw_kernel<<<(48 * 128 + 255) / 256, 256, 0, stream>>>(W1b, Wt3, 128, 40, 48);

  const int gGather = (N + 3) / 4;
  const int gGemm = (N + 63) / 64;

  // conv1
  gather64_kernel<<<gGather, 256, 0, stream>>>(x, rowptr, col, xa, N);
  gemm_mfma<64, 128, true><<<gGemm, 256, 0, stream>>>(xa, Wt1, b1a, mid, N, 128);
  gemm_mfma<128, 128, true><<<gGemm, 256, 0, stream>>>(mid, Wt2, b2a, h, N, 128);

  // conv2
  gather128_kernel<<<gGather, 256, 0, stream>>>((const unsigned int*)h, rowptr, col,
                                                (unsigned int*)ha, N);
  gemm_mfma<128, 48, true><<<gGemm, 256, 0, stream>>>(ha, Wt3, b1b, mid2, N, 40);
  gemm_lsm_kernel<<<1024, 256, 0, stream>>>(mid2, W2b, b2b, out, N);
}